// Round 1
// baseline (12.394 us; speedup 1.0000x reference)
//
#include <hip/hip_runtime.h>

// out[b,n,k] = |scale| * sum_d (table[d,k] - x[b,n,d])^2
//            = |scale| * ( T2[k] + X2[b,n] - 2 * dot(x[b,n,:], table[:,k]) )
// B=4, N=2048, D=64, K=256. All fp32.
//
// Strategy: one thread per k (256 threads/block = 4 waves), each block
// processes ROWS=8 (b,n) rows. x rows staged in LDS (broadcast reads are
// conflict-free); table read coalesced from L2 (64 KB, fully L2-resident);
// inner loop is 1 FMA per (d,row) via the expanded quadratic form.

#define TD_D    64
#define TD_K    256
#define TD_ROWS 8

__global__ void TableDistance_5669356831001_kernel(
    const float* __restrict__ x,      // [B*N, D]
    const float* __restrict__ table,  // [D, K]
    const float* __restrict__ scale,  // [1]
    float* __restrict__ out)          // [B*N, K]
{
    const int k    = threadIdx.x;               // 0..255
    const int row0 = blockIdx.x * TD_ROWS;      // base row index

    __shared__ float xs[TD_ROWS][TD_D];
    __shared__ float x2s[TD_ROWS];

    // Cooperative load: ROWS*D = 512 floats by 256 threads (2 each), coalesced.
    const float* xbase = x + (size_t)row0 * TD_D;
    float* xs_flat = &xs[0][0];
    #pragma unroll
    for (int i = 0; i < (TD_ROWS * TD_D) / 256; ++i) {
        xs_flat[threadIdx.x + i * 256] = xbase[threadIdx.x + i * 256];
    }
    __syncthreads();

    // Per-row ||x||^2 computed by the first ROWS threads (tiny: 8*64 FMAs).
    if (threadIdx.x < TD_ROWS) {
        float s = 0.f;
        #pragma unroll
        for (int d = 0; d < TD_D; ++d) {
            float v = xs[threadIdx.x][d];
            s = fmaf(v, v, s);
        }
        x2s[threadIdx.x] = s;
    }
    __syncthreads();

    // Main loop: per thread, T2[k] + dot products against ROWS rows.
    float acc[TD_ROWS];
    #pragma unroll
    for (int r = 0; r < TD_ROWS; ++r) acc[r] = 0.f;
    float t2 = 0.f;

    #pragma unroll
    for (int d = 0; d < TD_D; ++d) {
        float t = table[d * TD_K + k];   // coalesced across the wave, L2-hit
        t2 = fmaf(t, t, t2);
        #pragma unroll
        for (int r = 0; r < TD_ROWS; ++r) {
            acc[r] = fmaf(t, xs[r][d], acc[r]);   // LDS broadcast read
        }
    }

    const float s = fabsf(scale[0]);
    float* obase = out + (size_t)row0 * TD_K + k;
    #pragma unroll
    for (int r = 0; r < TD_ROWS; ++r) {
        obase[r * TD_K] = s * (t2 + x2s[r] - 2.0f * acc[r]);
    }
}

extern "C" void kernel_launch(void* const* d_in, const int* in_sizes, int n_in,
                              void* d_out, int out_size, void* d_ws, size_t ws_size,
                              hipStream_t stream) {
    const float* x     = (const float*)d_in[0];   // [4,2048,64]
    const float* table = (const float*)d_in[1];   // [1,1,64,256]
    const float* scale = (const float*)d_in[2];   // [1,1,1]
    float* out = (float*)d_out;                   // [4,2048,256]

    const int nrows = 4 * 2048;                   // 8192
    const int grid  = nrows / TD_ROWS;            // 1024 blocks
    TableDistance_5669356831001_kernel<<<grid, TD_K, 0, stream>>>(x, table, scale, out);
}